// Round 3
// baseline (1902.184 us; speedup 1.0000x reference)
//
#include <hip/hip_runtime.h>

#define NN 50000
#define EE 800000
#define GG 64

// ---------------- CSR build ----------------

__global__ void hist_kernel(const int* __restrict__ ei, int* __restrict__ deg) {
    int e = blockIdx.x * 256 + threadIdx.x;
    if (e < EE) atomicAdd(&deg[ei[EE + e]], 1);
}

__global__ void scan1_kernel(const int* __restrict__ deg, int* __restrict__ offs,
                             int* __restrict__ bsum) {
    __shared__ int lds[1024];
    int i = blockIdx.x * 1024 + threadIdx.x;
    int v = (i < NN) ? deg[i] : 0;
    lds[threadIdx.x] = v;
    __syncthreads();
    for (int d = 1; d < 1024; d <<= 1) {
        int t = (threadIdx.x >= d) ? lds[threadIdx.x - d] : 0;
        __syncthreads();
        lds[threadIdx.x] += t;
        __syncthreads();
    }
    int incl = lds[threadIdx.x];
    if (i < NN) offs[i] = incl - v;
    if (threadIdx.x == 1023) bsum[blockIdx.x] = incl;
}

__global__ void scan2_kernel(int* bsum, int nb) {
    if (threadIdx.x == 0 && blockIdx.x == 0) {
        int run = 0;
        for (int b = 0; b < nb; ++b) { int t = bsum[b]; bsum[b] = run; run += t; }
    }
}

__global__ void scan3_kernel(int* __restrict__ offs, int* __restrict__ cursor,
                             const int* __restrict__ bsum) {
    int i = blockIdx.x * 1024 + threadIdx.x;
    if (i < NN) {
        int o = offs[i] + bsum[blockIdx.x];
        offs[i] = o;
        cursor[i] = o;
    }
    if (i == 0 && blockIdx.x == 0) offs[NN] = EE;
}

__global__ void scatter_kernel(const int* __restrict__ ei, int* __restrict__ cursor,
                               int* __restrict__ srcs) {
    int e = blockIdx.x * 256 + threadIdx.x;
    if (e < EE) {
        int s = ei[e];
        int d = ei[EE + e];
        int pos = atomicAdd(&cursor[d], 1);
        srcs[pos] = s;
    }
}

// ---------------- GIN aggregation, prev-layer BN2+ReLU fused ----------------
// wave = 1 node. lane = (g,l): g=lane>>3 edge slot, l=lane&7 dim chunk [l*16,l*16+16).
// Each round: 8 edges gathered in parallel, 4 dwordx4 per lane, no shfl on the
// load path. Cross-group reduce via shfl_xor butterfly at the end.

template <bool BN>
__global__ __launch_bounds__(256) void agg_kernel(const float* __restrict__ x,
                                                  const int* __restrict__ offs,
                                                  const int* __restrict__ srcs,
                                                  const float* __restrict__ epsp, int layer,
                                                  const float* __restrict__ sb,
                                                  float* __restrict__ h0) {
    int node = blockIdx.x * 4 + (threadIdx.x >> 6);
    if (node >= NN) return;
    int lane = threadIdx.x & 63;
    int g = lane >> 3;
    int l = lane & 7;
    float4 sc[4], sh[4];
    if (BN) {
#pragma unroll
        for (int j = 0; j < 4; ++j) {
            sc[j] = ((const float4*)sb)[l * 4 + j];
            sh[j] = ((const float4*)(sb + 128))[l * 4 + j];
        }
    }
    float4 acc[4];
#pragma unroll
    for (int j = 0; j < 4; ++j) acc[j] = make_float4(0.f, 0.f, 0.f, 0.f);
    int beg = offs[node], end = offs[node + 1];
    int sI = (beg + g < end) ? srcs[beg + g] : 0;
    for (int base = beg; base + g < end; base += 8) {
        int sN = (base + 8 + g < end) ? srcs[base + 8 + g] : 0;
        const float4* row = (const float4*)(x + (size_t)sI * 128) + l * 4;
#pragma unroll
        for (int j = 0; j < 4; ++j) {
            float4 v = row[j];
            if (BN) {
                v.x = fmaxf(fmaf(v.x, sc[j].x, sh[j].x), 0.f);
                v.y = fmaxf(fmaf(v.y, sc[j].y, sh[j].y), 0.f);
                v.z = fmaxf(fmaf(v.z, sc[j].z, sh[j].z), 0.f);
                v.w = fmaxf(fmaf(v.w, sc[j].w, sh[j].w), 0.f);
            }
            acc[j].x += v.x; acc[j].y += v.y; acc[j].z += v.z; acc[j].w += v.w;
        }
        sI = sN;
    }
    // self term on group 0
    float e1 = 1.0f + epsp[layer];
    if (g == 0) {
        const float4* row = (const float4*)(x + (size_t)node * 128) + l * 4;
#pragma unroll
        for (int j = 0; j < 4; ++j) {
            float4 v = row[j];
            if (BN) {
                v.x = fmaxf(fmaf(v.x, sc[j].x, sh[j].x), 0.f);
                v.y = fmaxf(fmaf(v.y, sc[j].y, sh[j].y), 0.f);
                v.z = fmaxf(fmaf(v.z, sc[j].z, sh[j].z), 0.f);
                v.w = fmaxf(fmaf(v.w, sc[j].w, sh[j].w), 0.f);
            }
            acc[j].x = fmaf(e1, v.x, acc[j].x);
            acc[j].y = fmaf(e1, v.y, acc[j].y);
            acc[j].z = fmaf(e1, v.z, acc[j].z);
            acc[j].w = fmaf(e1, v.w, acc[j].w);
        }
    }
    // butterfly across the 8 groups
#pragma unroll
    for (int d = 8; d < 64; d <<= 1) {
#pragma unroll
        for (int j = 0; j < 4; ++j) {
            acc[j].x += __shfl_xor(acc[j].x, d);
            acc[j].y += __shfl_xor(acc[j].y, d);
            acc[j].z += __shfl_xor(acc[j].z, d);
            acc[j].w += __shfl_xor(acc[j].w, d);
        }
    }
    if (g == 0) {
        float4* o = (float4*)(h0 + (size_t)node * 128) + l * 4;
#pragma unroll
        for (int j = 0; j < 4; ++j) o[j] = acc[j];
    }
}

// ---------------- GEMM1 + fused stats/finalize: y1 = h0 (Nx128) @ W (128x64) ----------------
// 4 threads per node, 16 output channels each.

__global__ __launch_bounds__(256) void gemm1_kernel(const float* __restrict__ h0,
                                                    const float* __restrict__ W,
                                                    float* __restrict__ y,
                                                    float* __restrict__ stats,
                                                    int* __restrict__ cnt, int nblocks,
                                                    const float* __restrict__ bg,
                                                    const float* __restrict__ bb,
                                                    float* __restrict__ sb) {
    __shared__ float lW[128 * 64];
    for (int t = threadIdx.x; t < 2048; t += 256)
        ((float4*)lW)[t] = ((const float4*)W)[t];
    __syncthreads();
    int t = blockIdx.x * 256 + threadIdx.x;
    int n = t >> 2;
    int q = t & 3;  // channels [q*16, q*16+16)
    float acc[16];
#pragma unroll
    for (int j = 0; j < 16; ++j) acc[j] = 0.f;
    if (n < NN) {
        const float4* xr = (const float4*)(h0 + (size_t)n * 128);
#pragma unroll 1
        for (int k4 = 0; k4 < 32; ++k4) {
            float4 xv = xr[k4];
#pragma unroll
            for (int kk = 0; kk < 4; ++kk) {
                float xk = (kk == 0) ? xv.x : (kk == 1) ? xv.y : (kk == 2) ? xv.z : xv.w;
                const float4* wr = (const float4*)(lW + (k4 * 4 + kk) * 64 + q * 16);
#pragma unroll
                for (int j = 0; j < 4; ++j) {
                    float4 wv = wr[j];
                    acc[4 * j + 0] = fmaf(xk, wv.x, acc[4 * j + 0]);
                    acc[4 * j + 1] = fmaf(xk, wv.y, acc[4 * j + 1]);
                    acc[4 * j + 2] = fmaf(xk, wv.z, acc[4 * j + 2]);
                    acc[4 * j + 3] = fmaf(xk, wv.w, acc[4 * j + 3]);
                }
            }
        }
        float4* yr = (float4*)(y + (size_t)n * 64 + q * 16);
#pragma unroll
        for (int j = 0; j < 4; ++j)
            yr[j] = make_float4(acc[4 * j], acc[4 * j + 1], acc[4 * j + 2], acc[4 * j + 3]);
    }
    // stats: butterfly preserving q = lane&3
    float s2[16];
#pragma unroll
    for (int j = 0; j < 16; ++j) s2[j] = acc[j] * acc[j];
#pragma unroll
    for (int d = 4; d < 64; d <<= 1) {
#pragma unroll
        for (int j = 0; j < 16; ++j) {
            acc[j] += __shfl_xor(acc[j], d);
            s2[j] += __shfl_xor(s2[j], d);
        }
    }
    __shared__ float lst[4][128];
    int wv = threadIdx.x >> 6, ln = threadIdx.x & 63;
    if (ln < 4) {
#pragma unroll
        for (int j = 0; j < 16; ++j) {
            lst[wv][ln * 16 + j] = acc[j];
            lst[wv][64 + ln * 16 + j] = s2[j];
        }
    }
    __syncthreads();
    if (threadIdx.x < 128) {
        float v = lst[0][threadIdx.x] + lst[1][threadIdx.x] + lst[2][threadIdx.x] +
                  lst[3][threadIdx.x];
        atomicAdd(&stats[threadIdx.x], v);
    }
    __threadfence();
    __syncthreads();
    __shared__ int lastFlag;
    if (threadIdx.x == 0) lastFlag = (atomicAdd(cnt, 1) == nblocks - 1);
    __syncthreads();
    if (lastFlag && threadIdx.x < 64) {
        int c = threadIdx.x;
        float ss = atomicAdd(&stats[c], 0.f);
        float ss2 = atomicAdd(&stats[64 + c], 0.f);
        float mu = ss * (1.0f / NN);
        float var = ss2 * (1.0f / NN) - mu * mu;
        float inv = rsqrtf(var + 1e-5f);
        float scv = bg[c] * inv;
        sb[c] = scv;
        sb[64 + c] = bb[c] - mu * scv;
    }
}

// ---------------- GEMM2 + fused stats/finalize: y2 = relu(bn1(y1)) (Nx64) @ W (64x128) ----
// 4 threads per node, 32 output channels each.

__global__ __launch_bounds__(256) void gemm2_kernel(const float* __restrict__ y1,
                                                    const float* __restrict__ W,
                                                    const float* __restrict__ sb1,
                                                    float* __restrict__ y2,
                                                    float* __restrict__ stats,
                                                    int* __restrict__ cnt, int nblocks,
                                                    const float* __restrict__ bg,
                                                    const float* __restrict__ bb,
                                                    float* __restrict__ sb2) {
    __shared__ float lW[64 * 128];
    __shared__ float lsb[128];
    for (int t = threadIdx.x; t < 2048; t += 256)
        ((float4*)lW)[t] = ((const float4*)W)[t];
    if (threadIdx.x < 128) lsb[threadIdx.x] = sb1[threadIdx.x];
    __syncthreads();
    int t = blockIdx.x * 256 + threadIdx.x;
    int n = t >> 2;
    int q = t & 3;  // channels [q*32, q*32+32)
    float acc[32];
#pragma unroll
    for (int j = 0; j < 32; ++j) acc[j] = 0.f;
    if (n < NN) {
        const float4* xr = (const float4*)(y1 + (size_t)n * 64);
#pragma unroll 1
        for (int k4 = 0; k4 < 16; ++k4) {
            float4 xv = xr[k4];
#pragma unroll
            for (int kk = 0; kk < 4; ++kk) {
                int k = k4 * 4 + kk;
                float raw = (kk == 0) ? xv.x : (kk == 1) ? xv.y : (kk == 2) ? xv.z : xv.w;
                float v = fmaxf(fmaf(raw, lsb[k], lsb[64 + k]), 0.f);
                const float4* wr = (const float4*)(lW + k * 128 + q * 32);
#pragma unroll
                for (int j = 0; j < 8; ++j) {
                    float4 wv = wr[j];
                    acc[4 * j + 0] = fmaf(v, wv.x, acc[4 * j + 0]);
                    acc[4 * j + 1] = fmaf(v, wv.y, acc[4 * j + 1]);
                    acc[4 * j + 2] = fmaf(v, wv.z, acc[4 * j + 2]);
                    acc[4 * j + 3] = fmaf(v, wv.w, acc[4 * j + 3]);
                }
            }
        }
        float4* yr = (float4*)(y2 + (size_t)n * 128 + q * 32);
#pragma unroll
        for (int j = 0; j < 8; ++j)
            yr[j] = make_float4(acc[4 * j], acc[4 * j + 1], acc[4 * j + 2], acc[4 * j + 3]);
    }
    // stats chunked (2 x 16 channels)
    __shared__ float lst[4][256];
    int wv = threadIdx.x >> 6, ln = threadIdx.x & 63;
#pragma unroll
    for (int c0 = 0; c0 < 2; ++c0) {
        float s[16], s2[16];
#pragma unroll
        for (int j = 0; j < 16; ++j) {
            s[j] = acc[c0 * 16 + j];
            s2[j] = s[j] * s[j];
        }
#pragma unroll
        for (int d = 4; d < 64; d <<= 1) {
#pragma unroll
            for (int j = 0; j < 16; ++j) {
                s[j] += __shfl_xor(s[j], d);
                s2[j] += __shfl_xor(s2[j], d);
            }
        }
        if (ln < 4) {
#pragma unroll
            for (int j = 0; j < 16; ++j) {
                lst[wv][ln * 32 + c0 * 16 + j] = s[j];
                lst[wv][128 + ln * 32 + c0 * 16 + j] = s2[j];
            }
        }
    }
    __syncthreads();
    {
        float v = lst[0][threadIdx.x] + lst[1][threadIdx.x] + lst[2][threadIdx.x] +
                  lst[3][threadIdx.x];
        atomicAdd(&stats[threadIdx.x], v);
    }
    __threadfence();
    __syncthreads();
    __shared__ int lastFlag;
    if (threadIdx.x == 0) lastFlag = (atomicAdd(cnt, 1) == nblocks - 1);
    __syncthreads();
    if (lastFlag && threadIdx.x < 128) {
        int c = threadIdx.x;
        float ss = atomicAdd(&stats[c], 0.f);
        float ss2 = atomicAdd(&stats[128 + c], 0.f);
        float mu = ss * (1.0f / NN);
        float var = ss2 * (1.0f / NN) - mu * mu;
        float inv = rsqrtf(var + 1e-5f);
        float scv = bg[c] * inv;
        sb2[c] = scv;
        sb2[128 + c] = bb[c] - mu * scv;
    }
}

// ---------------- last layer: x = relu( relu(bn1(y1)) @ Wlast (64 x 2) ) ----------------

__global__ void gemm_last_kernel(const float* __restrict__ y1, const float* __restrict__ W,
                                 const float* __restrict__ sb, float* __restrict__ xl) {
    __shared__ float lw[128];
    if (threadIdx.x < 128) lw[threadIdx.x] = W[threadIdx.x];
    __syncthreads();
    int n = blockIdx.x * 256 + threadIdx.x;
    if (n >= NN) return;
    float a0 = 0.f, a1 = 0.f;
    const float* row = y1 + (size_t)n * 64;
#pragma unroll
    for (int k = 0; k < 64; ++k) {
        float v = fmaxf(fmaf(row[k], sb[k], sb[64 + k]), 0.f);
        a0 = fmaf(v, lw[2 * k + 0], a0);
        a1 = fmaf(v, lw[2 * k + 1], a1);
    }
    xl[2 * n + 0] = fmaxf(a0, 0.f);
    xl[2 * n + 1] = fmaxf(a1, 0.f);
}

// ---------------- mean pool over sorted batch via wave-segmented scan ----------------

__global__ void pool_accum_kernel(const float* __restrict__ xl, const int* __restrict__ batch,
                                  float* __restrict__ pool) {
    int n = blockIdx.x * 256 + threadIdx.x;
    int lane = threadIdx.x & 63;
    int g = -1;
    float v0 = 0.f, v1 = 0.f, c = 0.f;
    if (n < NN) {
        g = batch[n];
        v0 = xl[2 * n + 0];
        v1 = xl[2 * n + 1];
        c = 1.0f;
    }
    for (int d = 1; d < 64; d <<= 1) {
        int tg = __shfl_up(g, d);
        float t0 = __shfl_up(v0, d);
        float t1 = __shfl_up(v1, d);
        float tc = __shfl_up(c, d);
        if (lane >= d && tg == g) { v0 += t0; v1 += t1; c += tc; }
    }
    int gn = __shfl_down(g, 1);
    bool lastv = (lane == 63) || (gn != g);
    if (g >= 0 && lastv) {
        atomicAdd(&pool[g * 3 + 0], v0);
        atomicAdd(&pool[g * 3 + 1], v1);
        atomicAdd(&pool[g * 3 + 2], c);
    }
}

__global__ void pool_fin_kernel(const float* __restrict__ pool, float* __restrict__ out) {
    int t = threadIdx.x;
    if (t < GG * 2) {
        int g = t >> 1, j = t & 1;
        float cnt = pool[g * 3 + 2];
        out[t] = pool[g * 3 + j] / fmaxf(cnt, 1.0f);
    }
}

// ---------------- launch ----------------

extern "C" void kernel_launch(void* const* d_in, const int* in_sizes, int n_in,
                              void* d_out, int out_size, void* d_ws, size_t ws_size,
                              hipStream_t stream) {
    const float* x_in  = (const float*)d_in[0];
    const int*   ei    = (const int*)d_in[1];
    const int*   batch = (const int*)d_in[3];
    const float* W1    = (const float*)d_in[4];
    const float* bn1g  = (const float*)d_in[5];
    const float* bn1b  = (const float*)d_in[6];
    const float* W2    = (const float*)d_in[7];
    const float* bn2g  = (const float*)d_in[8];
    const float* bn2b  = (const float*)d_in[9];
    const float* Wlast = (const float*)d_in[10];
    const float* eps   = (const float*)d_in[11];
    float* out = (float*)d_out;

    char* ws = (char*)d_ws;
    size_t off = 0;
    auto alloc = [&](size_t bytes) -> char* {
        char* p = ws + off;
        off += (bytes + 255) & ~(size_t)255;
        return p;
    };
    // -- zeroed region first (one memset) --
    int*   deg      = (int*)alloc((size_t)NN * 4);
    float* statsall = (float*)alloc(16 * 256 * 4);
    int*   cnts     = (int*)alloc(16 * 4);
    float* pool     = (float*)alloc((size_t)GG * 3 * 4);
    size_t zero_len = off;
    // -- rest --
    float* sball  = (float*)alloc(16 * 256 * 4);
    int*   offs   = (int*)alloc((size_t)(NN + 1) * 4);
    int*   cursor = (int*)alloc((size_t)NN * 4);
    int*   bsum   = (int*)alloc(64 * 4);
    int*   srcs   = (int*)alloc((size_t)EE * 4);
    float* A      = (float*)alloc((size_t)NN * 128 * 4);  // raw y2 (next layer gather src)
    float* B      = (float*)alloc((size_t)NN * 128 * 4);  // h0
    float* Cb     = (float*)alloc((size_t)NN * 64 * 4);   // raw y1
    float* xlast  = (float*)alloc((size_t)NN * 2 * 4);
    (void)ws_size; (void)n_in; (void)in_sizes; (void)out_size;

    hipMemsetAsync(ws, 0, zero_len, stream);

    // CSR build (by dst)
    hist_kernel<<<(EE + 255) / 256, 256, 0, stream>>>(ei, deg);
    scan1_kernel<<<49, 1024, 0, stream>>>(deg, offs, bsum);
    scan2_kernel<<<1, 64, 0, stream>>>(bsum, 49);
    scan3_kernel<<<49, 1024, 0, stream>>>(offs, cursor, bsum);
    scatter_kernel<<<(EE + 255) / 256, 256, 0, stream>>>(ei, cursor, srcs);

    const int GB = (NN * 4 + 255) / 256;  // 782 blocks for gemm1/gemm2

    for (int i = 0; i < 7; ++i) {
        int s1 = 2 * i, s2 = 2 * i + 1;
        if (i == 0) {
            agg_kernel<false><<<(NN + 3) / 4, 256, 0, stream>>>(x_in, offs, srcs, eps, i,
                                                                nullptr, B);
        } else {
            agg_kernel<true><<<(NN + 3) / 4, 256, 0, stream>>>(A, offs, srcs, eps, i,
                                                               sball + (2 * i - 1) * 256, B);
        }
        gemm1_kernel<<<GB, 256, 0, stream>>>(B, W1 + (size_t)i * 128 * 64, Cb,
                                             statsall + s1 * 256, cnts + s1, GB,
                                             bn1g + i * 64, bn1b + i * 64, sball + s1 * 256);
        if (i < 6) {
            gemm2_kernel<<<GB, 256, 0, stream>>>(Cb, W2 + (size_t)i * 64 * 128,
                                                 sball + s1 * 256, A, statsall + s2 * 256,
                                                 cnts + s2, GB, bn2g + i * 128, bn2b + i * 128,
                                                 sball + s2 * 256);
        } else {
            gemm_last_kernel<<<(NN + 255) / 256, 256, 0, stream>>>(Cb, Wlast,
                                                                   sball + s1 * 256, xlast);
        }
    }

    pool_accum_kernel<<<(NN + 255) / 256, 256, 0, stream>>>(xlast, batch, pool);
    pool_fin_kernel<<<1, 128, 0, stream>>>(pool, out);
}

// Round 4
// 962.214 us; speedup vs baseline: 1.9769x; 1.9769x over previous
//
#include <hip/hip_runtime.h>

#define NN 50000
#define EE 800000
#define GG 64
#define BNEPS 1e-5f

// ---------------- CSR build ----------------

__global__ void hist_kernel(const int* __restrict__ ei, int* __restrict__ deg) {
    int e = blockIdx.x * 256 + threadIdx.x;
    if (e < EE) atomicAdd(&deg[ei[EE + e]], 1);
}

__global__ void scan1_kernel(const int* __restrict__ deg, int* __restrict__ offs,
                             int* __restrict__ bsum) {
    __shared__ int lds[1024];
    int i = blockIdx.x * 1024 + threadIdx.x;
    int v = (i < NN) ? deg[i] : 0;
    lds[threadIdx.x] = v;
    __syncthreads();
    for (int d = 1; d < 1024; d <<= 1) {
        int t = (threadIdx.x >= d) ? lds[threadIdx.x - d] : 0;
        __syncthreads();
        lds[threadIdx.x] += t;
        __syncthreads();
    }
    int incl = lds[threadIdx.x];
    if (i < NN) offs[i] = incl - v;
    if (threadIdx.x == 1023) bsum[blockIdx.x] = incl;
}

__global__ void scan2_kernel(int* bsum, int nb) {
    if (threadIdx.x == 0 && blockIdx.x == 0) {
        int run = 0;
        for (int b = 0; b < nb; ++b) { int t = bsum[b]; bsum[b] = run; run += t; }
    }
}

__global__ void scan3_kernel(int* __restrict__ offs, int* __restrict__ cursor,
                             const int* __restrict__ bsum) {
    int i = blockIdx.x * 1024 + threadIdx.x;
    if (i < NN) {
        int o = offs[i] + bsum[blockIdx.x];
        offs[i] = o;
        cursor[i] = o;
    }
    if (i == 0 && blockIdx.x == 0) offs[NN] = EE;
}

__global__ void scatter_kernel(const int* __restrict__ ei, int* __restrict__ cursor,
                               int* __restrict__ srcs) {
    int e = blockIdx.x * 256 + threadIdx.x;
    if (e < EE) {
        int s = ei[e];
        int d = ei[EE + e];
        int pos = atomicAdd(&cursor[d], 1);
        srcs[pos] = s;
    }
}

// ---------------- GIN aggregation, prev-layer BN2+ReLU fused (BN from raw stats) ------
// wave = 1 node. lane = (g,l): g=lane>>3 edge slot, l=lane&7 dim chunk [l*16,l*16+16).

template <bool BN>
__global__ __launch_bounds__(256) void agg_kernel(const float* __restrict__ x,
                                                  const int* __restrict__ offs,
                                                  const int* __restrict__ srcs,
                                                  const float* __restrict__ epsp, int layer,
                                                  const float* __restrict__ stats,
                                                  const float* __restrict__ bg,
                                                  const float* __restrict__ bb,
                                                  float* __restrict__ h0) {
    __shared__ float lsb[256];
    if (BN) {
        if (threadIdx.x < 128) {
            int c = threadIdx.x;
            float mu = stats[c] * (1.0f / NN);
            float var = stats[128 + c] * (1.0f / NN) - mu * mu;
            float inv = rsqrtf(var + BNEPS);
            float sc = bg[c] * inv;
            lsb[c] = sc;
            lsb[128 + c] = bb[c] - mu * sc;
        }
        __syncthreads();
    }
    int node = blockIdx.x * 4 + (threadIdx.x >> 6);
    if (node >= NN) return;
    int lane = threadIdx.x & 63;
    int g = lane >> 3;
    int l = lane & 7;
    float4 sc[4], sh[4];
    if (BN) {
#pragma unroll
        for (int j = 0; j < 4; ++j) {
            sc[j] = ((const float4*)lsb)[l * 4 + j];
            sh[j] = ((const float4*)(lsb + 128))[l * 4 + j];
        }
    }
    float4 acc[4];
#pragma unroll
    for (int j = 0; j < 4; ++j) acc[j] = make_float4(0.f, 0.f, 0.f, 0.f);
    int beg = offs[node], end = offs[node + 1];
    int sI = (beg + g < end) ? srcs[beg + g] : 0;
    for (int base = beg; base + g < end; base += 8) {
        int sN = (base + 8 + g < end) ? srcs[base + 8 + g] : 0;
        const float4* row = (const float4*)(x + (size_t)sI * 128) + l * 4;
#pragma unroll
        for (int j = 0; j < 4; ++j) {
            float4 v = row[j];
            if (BN) {
                v.x = fmaxf(fmaf(v.x, sc[j].x, sh[j].x), 0.f);
                v.y = fmaxf(fmaf(v.y, sc[j].y, sh[j].y), 0.f);
                v.z = fmaxf(fmaf(v.z, sc[j].z, sh[j].z), 0.f);
                v.w = fmaxf(fmaf(v.w, sc[j].w, sh[j].w), 0.f);
            }
            acc[j].x += v.x; acc[j].y += v.y; acc[j].z += v.z; acc[j].w += v.w;
        }
        sI = sN;
    }
    float e1 = 1.0f + epsp[layer];
    if (g == 0) {
        const float4* row = (const float4*)(x + (size_t)node * 128) + l * 4;
#pragma unroll
        for (int j = 0; j < 4; ++j) {
            float4 v = row[j];
            if (BN) {
                v.x = fmaxf(fmaf(v.x, sc[j].x, sh[j].x), 0.f);
                v.y = fmaxf(fmaf(v.y, sc[j].y, sh[j].y), 0.f);
                v.z = fmaxf(fmaf(v.z, sc[j].z, sh[j].z), 0.f);
                v.w = fmaxf(fmaf(v.w, sc[j].w, sh[j].w), 0.f);
            }
            acc[j].x = fmaf(e1, v.x, acc[j].x);
            acc[j].y = fmaf(e1, v.y, acc[j].y);
            acc[j].z = fmaf(e1, v.z, acc[j].z);
            acc[j].w = fmaf(e1, v.w, acc[j].w);
        }
    }
#pragma unroll
    for (int d = 8; d < 64; d <<= 1) {
#pragma unroll
        for (int j = 0; j < 4; ++j) {
            acc[j].x += __shfl_xor(acc[j].x, d);
            acc[j].y += __shfl_xor(acc[j].y, d);
            acc[j].z += __shfl_xor(acc[j].z, d);
            acc[j].w += __shfl_xor(acc[j].w, d);
        }
    }
    if (g == 0) {
        float4* o = (float4*)(h0 + (size_t)node * 128) + l * 4;
#pragma unroll
        for (int j = 0; j < 4; ++j) o[j] = acc[j];
    }
}

// ---------------- GEMM1: y1 = h0 (Nx128) @ W (128x64); plain-atomic stats epilogue ------
// thread = 4 nodes x 16 channels. q=tid&3 channel quad, slot=tid>>2.

__global__ __launch_bounds__(256) void gemm1_kernel(const float* __restrict__ h0,
                                                    const float* __restrict__ W,
                                                    float* __restrict__ y,
                                                    float* __restrict__ stats) {
    __shared__ float lW[128 * 64];
    for (int t = threadIdx.x; t < 2048; t += 256)
        ((float4*)lW)[t] = ((const float4*)W)[t];
    __syncthreads();
    int q = threadIdx.x & 3;
    int slot = threadIdx.x >> 2;
    int n0 = blockIdx.x * 256 + slot * 4;
    bool vld[4];
    const float4* xr[4];
#pragma unroll
    for (int r = 0; r < 4; ++r) {
        vld[r] = (n0 + r) < NN;
        xr[r] = (const float4*)(h0 + (size_t)(vld[r] ? n0 + r : 0) * 128);
    }
    float acc[4][16];
#pragma unroll
    for (int r = 0; r < 4; ++r)
#pragma unroll
        for (int j = 0; j < 16; ++j) acc[r][j] = 0.f;
    const float4 z4 = make_float4(0.f, 0.f, 0.f, 0.f);
#pragma unroll 2
    for (int k4 = 0; k4 < 32; ++k4) {
        float4 xv[4];
#pragma unroll
        for (int r = 0; r < 4; ++r) xv[r] = vld[r] ? xr[r][k4] : z4;
#pragma unroll
        for (int kk = 0; kk < 4; ++kk) {
            const float4* wr = (const float4*)(lW + (k4 * 4 + kk) * 64 + q * 16);
            float4 w0 = wr[0], w1 = wr[1], w2 = wr[2], w3 = wr[3];
#pragma unroll
            for (int r = 0; r < 4; ++r) {
                float a = (kk == 0) ? xv[r].x : (kk == 1) ? xv[r].y : (kk == 2) ? xv[r].z
                                                                                : xv[r].w;
                acc[r][0] = fmaf(a, w0.x, acc[r][0]);
                acc[r][1] = fmaf(a, w0.y, acc[r][1]);
                acc[r][2] = fmaf(a, w0.z, acc[r][2]);
                acc[r][3] = fmaf(a, w0.w, acc[r][3]);
                acc[r][4] = fmaf(a, w1.x, acc[r][4]);
                acc[r][5] = fmaf(a, w1.y, acc[r][5]);
                acc[r][6] = fmaf(a, w1.z, acc[r][6]);
                acc[r][7] = fmaf(a, w1.w, acc[r][7]);
                acc[r][8] = fmaf(a, w2.x, acc[r][8]);
                acc[r][9] = fmaf(a, w2.y, acc[r][9]);
                acc[r][10] = fmaf(a, w2.z, acc[r][10]);
                acc[r][11] = fmaf(a, w2.w, acc[r][11]);
                acc[r][12] = fmaf(a, w3.x, acc[r][12]);
                acc[r][13] = fmaf(a, w3.y, acc[r][13]);
                acc[r][14] = fmaf(a, w3.z, acc[r][14]);
                acc[r][15] = fmaf(a, w3.w, acc[r][15]);
            }
        }
    }
#pragma unroll
    for (int r = 0; r < 4; ++r) {
        if (vld[r]) {
            float4* yr = (float4*)(y + (size_t)(n0 + r) * 64 + q * 16);
#pragma unroll
            for (int j = 0; j < 4; ++j)
                yr[j] = make_float4(acc[r][4 * j], acc[r][4 * j + 1], acc[r][4 * j + 2],
                                    acc[r][4 * j + 3]);
        }
    }
    // stats (invalid nodes contribute exact zeros)
    float s[16], s2[16];
#pragma unroll
    for (int j = 0; j < 16; ++j) {
        s[j] = acc[0][j] + acc[1][j] + acc[2][j] + acc[3][j];
        s2[j] = acc[0][j] * acc[0][j] + acc[1][j] * acc[1][j] + acc[2][j] * acc[2][j] +
                acc[3][j] * acc[3][j];
    }
#pragma unroll
    for (int d = 4; d < 64; d <<= 1)
#pragma unroll
        for (int j = 0; j < 16; ++j) {
            s[j] += __shfl_xor(s[j], d);
            s2[j] += __shfl_xor(s2[j], d);
        }
    __shared__ float lst[4][128];
    int wv = threadIdx.x >> 6, ln = threadIdx.x & 63;
    if (ln < 4) {
#pragma unroll
        for (int j = 0; j < 16; ++j) {
            lst[wv][ln * 16 + j] = s[j];
            lst[wv][64 + ln * 16 + j] = s2[j];
        }
    }
    __syncthreads();
    if (threadIdx.x < 128)
        atomicAdd(&stats[threadIdx.x], lst[0][threadIdx.x] + lst[1][threadIdx.x] +
                                           lst[2][threadIdx.x] + lst[3][threadIdx.x]);
}

// ---------------- GEMM2: y2 = relu(bn1(y1)) (Nx64) @ W (64x128); stats epilogue --------
// thread = 4 nodes x 16 channels. q=tid&7, slot=tid>>3. BN1 computed in prologue.

__global__ __launch_bounds__(256) void gemm2_kernel(const float* __restrict__ y1,
                                                    const float* __restrict__ W,
                                                    const float* __restrict__ stats1,
                                                    const float* __restrict__ bg,
                                                    const float* __restrict__ bb,
                                                    float* __restrict__ y2,
                                                    float* __restrict__ stats2) {
    __shared__ float lW[64 * 128];
    __shared__ float lsb[128];
    for (int t = threadIdx.x; t < 2048; t += 256)
        ((float4*)lW)[t] = ((const float4*)W)[t];
    if (threadIdx.x < 64) {
        int c = threadIdx.x;
        float mu = stats1[c] * (1.0f / NN);
        float var = stats1[64 + c] * (1.0f / NN) - mu * mu;
        float inv = rsqrtf(var + BNEPS);
        float sc = bg[c] * inv;
        lsb[c] = sc;
        lsb[64 + c] = bb[c] - mu * sc;
    }
    __syncthreads();
    int q = threadIdx.x & 7;
    int slot = threadIdx.x >> 3;
    int n0 = blockIdx.x * 128 + slot * 4;
    bool vld[4];
    const float4* xr[4];
#pragma unroll
    for (int r = 0; r < 4; ++r) {
        vld[r] = (n0 + r) < NN;
        xr[r] = (const float4*)(y1 + (size_t)(vld[r] ? n0 + r : 0) * 64);
    }
    float acc[4][16];
#pragma unroll
    for (int r = 0; r < 4; ++r)
#pragma unroll
        for (int j = 0; j < 16; ++j) acc[r][j] = 0.f;
    const float4 z4 = make_float4(0.f, 0.f, 0.f, 0.f);
#pragma unroll 2
    for (int k4 = 0; k4 < 16; ++k4) {
        float4 xv[4];
#pragma unroll
        for (int r = 0; r < 4; ++r) xv[r] = vld[r] ? xr[r][k4] : z4;
#pragma unroll
        for (int kk = 0; kk < 4; ++kk) {
            int k = k4 * 4 + kk;
            float sck = lsb[k], shk = lsb[64 + k];
            const float4* wr = (const float4*)(lW + k * 128 + q * 16);
            float4 w0 = wr[0], w1 = wr[1], w2 = wr[2], w3 = wr[3];
#pragma unroll
            for (int r = 0; r < 4; ++r) {
                float raw = (kk == 0) ? xv[r].x : (kk == 1) ? xv[r].y : (kk == 2) ? xv[r].z
                                                                                  : xv[r].w;
                float a = fmaxf(fmaf(raw, sck, shk), 0.f);
                acc[r][0] = fmaf(a, w0.x, acc[r][0]);
                acc[r][1] = fmaf(a, w0.y, acc[r][1]);
                acc[r][2] = fmaf(a, w0.z, acc[r][2]);
                acc[r][3] = fmaf(a, w0.w, acc[r][3]);
                acc[r][4] = fmaf(a, w1.x, acc[r][4]);
                acc[r][5] = fmaf(a, w1.y, acc[r][5]);
                acc[r][6] = fmaf(a, w1.z, acc[r][6]);
                acc[r][7] = fmaf(a, w1.w, acc[r][7]);
                acc[r][8] = fmaf(a, w2.x, acc[r][8]);
                acc[r][9] = fmaf(a, w2.y, acc[r][9]);
                acc[r][10] = fmaf(a, w2.z, acc[r][10]);
                acc[r][11] = fmaf(a, w2.w, acc[r][11]);
                acc[r][12] = fmaf(a, w3.x, acc[r][12]);
                acc[r][13] = fmaf(a, w3.y, acc[r][13]);
                acc[r][14] = fmaf(a, w3.z, acc[r][14]);
                acc[r][15] = fmaf(a, w3.w, acc[r][15]);
            }
        }
    }
#pragma unroll
    for (int r = 0; r < 4; ++r) {
        if (vld[r]) {
            float4* yr = (float4*)(y2 + (size_t)(n0 + r) * 128 + q * 16);
#pragma unroll
            for (int j = 0; j < 4; ++j)
                yr[j] = make_float4(acc[r][4 * j], acc[r][4 * j + 1], acc[r][4 * j + 2],
                                    acc[r][4 * j + 3]);
        }
    }
    float s[16], s2[16];
#pragma unroll
    for (int j = 0; j < 16; ++j) {
        s[j] = acc[0][j] + acc[1][j] + acc[2][j] + acc[3][j];
        s2[j] = acc[0][j] * acc[0][j] + acc[1][j] * acc[1][j] + acc[2][j] * acc[2][j] +
                acc[3][j] * acc[3][j];
    }
#pragma unroll
    for (int d = 8; d < 64; d <<= 1)
#pragma unroll
        for (int j = 0; j < 16; ++j) {
            s[j] += __shfl_xor(s[j], d);
            s2[j] += __shfl_xor(s2[j], d);
        }
    __shared__ float lst[4][256];
    int wv = threadIdx.x >> 6, ln = threadIdx.x & 63;
    if (ln < 8) {
#pragma unroll
        for (int j = 0; j < 16; ++j) {
            lst[wv][ln * 16 + j] = s[j];
            lst[wv][128 + ln * 16 + j] = s2[j];
        }
    }
    __syncthreads();
    atomicAdd(&stats2[threadIdx.x], lst[0][threadIdx.x] + lst[1][threadIdx.x] +
                                        lst[2][threadIdx.x] + lst[3][threadIdx.x]);
}

// ---------------- last layer: x = relu( relu(bn1(y1)) @ Wlast (64x2) ) ----------------

__global__ void gemm_last_kernel(const float* __restrict__ y1, const float* __restrict__ W,
                                 const float* __restrict__ stats1,
                                 const float* __restrict__ bg, const float* __restrict__ bb,
                                 float* __restrict__ xl) {
    __shared__ float lw[128];
    __shared__ float lsb[128];
    if (threadIdx.x < 128) lw[threadIdx.x] = W[threadIdx.x];
    if (threadIdx.x < 64) {
        int c = threadIdx.x;
        float mu = stats1[c] * (1.0f / NN);
        float var = stats1[64 + c] * (1.0f / NN) - mu * mu;
        float inv = rsqrtf(var + BNEPS);
        float sc = bg[c] * inv;
        lsb[c] = sc;
        lsb[64 + c] = bb[c] - mu * sc;
    }
    __syncthreads();
    int n = blockIdx.x * 256 + threadIdx.x;
    if (n >= NN) return;
    float a0 = 0.f, a1 = 0.f;
    const float* row = y1 + (size_t)n * 64;
#pragma unroll
    for (int k = 0; k < 64; ++k) {
        float v = fmaxf(fmaf(row[k], lsb[k], lsb[64 + k]), 0.f);
        a0 = fmaf(v, lw[2 * k + 0], a0);
        a1 = fmaf(v, lw[2 * k + 1], a1);
    }
    xl[2 * n + 0] = fmaxf(a0, 0.f);
    xl[2 * n + 1] = fmaxf(a1, 0.f);
}

// ---------------- mean pool over sorted batch via wave-segmented scan ----------------

__global__ void pool_accum_kernel(const float* __restrict__ xl, const int* __restrict__ batch,
                                  float* __restrict__ pool) {
    int n = blockIdx.x * 256 + threadIdx.x;
    int lane = threadIdx.x & 63;
    int g = -1;
    float v0 = 0.f, v1 = 0.f, c = 0.f;
    if (n < NN) {
        g = batch[n];
        v0 = xl[2 * n + 0];
        v1 = xl[2 * n + 1];
        c = 1.0f;
    }
    for (int d = 1; d < 64; d <<= 1) {
        int tg = __shfl_up(g, d);
        float t0 = __shfl_up(v0, d);
        float t1 = __shfl_up(v1, d);
        float tc = __shfl_up(c, d);
        if (lane >= d && tg == g) { v0 += t0; v1 += t1; c += tc; }
    }
    int gn = __shfl_down(g, 1);
    bool lastv = (lane == 63) || (gn != g);
    if (g >= 0 && lastv) {
        atomicAdd(&pool[g * 3 + 0], v0);
        atomicAdd(&pool[g * 3 + 1], v1);
        atomicAdd(&pool[g * 3 + 2], c);
    }
}

__global__ void pool_fin_kernel(const float* __restrict__ pool, float* __restrict__ out) {
    int t = threadIdx.x;
    if (t < GG * 2) {
        int g = t >> 1, j = t & 1;
        float cnt = pool[g * 3 + 2];
        out[t] = pool[g * 3 + j] / fmaxf(cnt, 1.0f);
    }
}

// ---------------- launch ----------------

extern "C" void kernel_launch(void* const* d_in, const int* in_sizes, int n_in,
                              void* d_out, int out_size, void* d_ws, size_t ws_size,
                              hipStream_t stream) {
    const float* x_in  = (const float*)d_in[0];
    const int*   ei    = (const int*)d_in[1];
    const int*   batch = (const int*)d_in[3];
    const float* W1    = (const float*)d_in[4];
    const float* bn1g  = (const float*)d_in[5];
    const float* bn1b  = (const float*)d_in[6];
    const float* W2    = (const float*)d_in[7];
    const float* bn2g  = (const float*)d_in[8];
    const float* bn2b  = (const float*)d_in[9];
    const float* Wlast = (const float*)d_in[10];
    const float* eps   = (const float*)d_in[11];
    float* out = (float*)d_out;

    char* ws = (char*)d_ws;
    size_t off = 0;
    auto alloc = [&](size_t bytes) -> char* {
        char* p = ws + off;
        off += (bytes + 255) & ~(size_t)255;
        return p;
    };
    // -- zeroed region first (one memset) --
    int*   deg      = (int*)alloc((size_t)NN * 4);
    float* statsall = (float*)alloc(16 * 256 * 4);  // slot s: [0..C) sum, [C..2C) sumsq
    float* pool     = (float*)alloc((size_t)GG * 3 * 4);
    size_t zero_len = off;
    // -- rest --
    int*   offs   = (int*)alloc((size_t)(NN + 1) * 4);
    int*   cursor = (int*)alloc((size_t)NN * 4);
    int*   bsum   = (int*)alloc(64 * 4);
    int*   srcs   = (int*)alloc((size_t)EE * 4);
    float* A      = (float*)alloc((size_t)NN * 128 * 4);  // raw y2 (next layer gather src)
    float* B      = (float*)alloc((size_t)NN * 128 * 4);  // h0
    float* Cb     = (float*)alloc((size_t)NN * 64 * 4);   // raw y1
    float* xlast  = (float*)alloc((size_t)NN * 2 * 4);
    (void)ws_size; (void)n_in; (void)in_sizes; (void)out_size;

    hipMemsetAsync(ws, 0, zero_len, stream);

    // CSR build (by dst)
    hist_kernel<<<(EE + 255) / 256, 256, 0, stream>>>(ei, deg);
    scan1_kernel<<<49, 1024, 0, stream>>>(deg, offs, bsum);
    scan2_kernel<<<1, 64, 0, stream>>>(bsum, 49);
    scan3_kernel<<<49, 1024, 0, stream>>>(offs, cursor, bsum);
    scatter_kernel<<<(EE + 255) / 256, 256, 0, stream>>>(ei, cursor, srcs);

    const int GB1 = (NN + 255) / 256;  // 196 (256 nodes/block)
    const int GB2 = (NN + 127) / 128;  // 391 (128 nodes/block)

    for (int i = 0; i < 7; ++i) {
        int s1 = 2 * i, s2 = 2 * i + 1;
        if (i == 0) {
            agg_kernel<false><<<(NN + 3) / 4, 256, 0, stream>>>(x_in, offs, srcs, eps, i,
                                                                nullptr, nullptr, nullptr, B);
        } else {
            agg_kernel<true><<<(NN + 3) / 4, 256, 0, stream>>>(
                A, offs, srcs, eps, i, statsall + (2 * i - 1) * 256, bn2g + (i - 1) * 128,
                bn2b + (i - 1) * 128, B);
        }
        gemm1_kernel<<<GB1, 256, 0, stream>>>(B, W1 + (size_t)i * 128 * 64, Cb,
                                              statsall + s1 * 256);
        if (i < 6) {
            gemm2_kernel<<<GB2, 256, 0, stream>>>(Cb, W2 + (size_t)i * 64 * 128,
                                                  statsall + s1 * 256, bn1g + i * 64,
                                                  bn1b + i * 64, A, statsall + s2 * 256);
        } else {
            gemm_last_kernel<<<(NN + 255) / 256, 256, 0, stream>>>(
                Cb, Wlast, statsall + s1 * 256, bn1g + i * 64, bn1b + i * 64, xlast);
        }
    }

    pool_accum_kernel<<<(NN + 255) / 256, 256, 0, stream>>>(xlast, batch, pool);
    pool_fin_kernel<<<1, 128, 0, stream>>>(pool, out);
}

// Round 5
// 838.004 us; speedup vs baseline: 2.2699x; 1.1482x over previous
//
#include <hip/hip_runtime.h>
#include <hip/hip_fp16.h>

#define NN 50000
#define EE 800000
#define GG 64
#define BNEPS 1e-5f

__device__ inline float2 h2f(unsigned int u) {
    __half2 h = __builtin_bit_cast(__half2, u);
    return __half22float2(h);
}
__device__ inline unsigned int f2h(float a, float b) {
    __half2 h = __float22half2_rn(make_float2(a, b));
    return __builtin_bit_cast(unsigned int, h);
}

// ---------------- CSR build ----------------

__global__ void hist_kernel(const int* __restrict__ ei, int* __restrict__ deg) {
    int e = blockIdx.x * 256 + threadIdx.x;
    if (e < EE) atomicAdd(&deg[ei[EE + e]], 1);
}

__global__ void scan1_kernel(const int* __restrict__ deg, int* __restrict__ offs,
                             int* __restrict__ bsum) {
    __shared__ int lds[1024];
    int i = blockIdx.x * 1024 + threadIdx.x;
    int v = (i < NN) ? deg[i] : 0;
    lds[threadIdx.x] = v;
    __syncthreads();
    for (int d = 1; d < 1024; d <<= 1) {
        int t = (threadIdx.x >= d) ? lds[threadIdx.x - d] : 0;
        __syncthreads();
        lds[threadIdx.x] += t;
        __syncthreads();
    }
    int incl = lds[threadIdx.x];
    if (i < NN) offs[i] = incl - v;
    if (threadIdx.x == 1023) bsum[blockIdx.x] = incl;
}

__global__ void scan3_kernel(int* __restrict__ offs, int* __restrict__ cursor,
                             const int* __restrict__ bsum) {
    __shared__ int base;
    if (threadIdx.x == 0) {
        int r = 0;
        for (int b = 0; b < (int)blockIdx.x; ++b) r += bsum[b];
        base = r;
    }
    __syncthreads();
    int i = blockIdx.x * 1024 + threadIdx.x;
    if (i < NN) {
        int o = offs[i] + base;
        offs[i] = o;
        cursor[i] = o;
    }
    if (i == 0 && blockIdx.x == 0) offs[NN] = EE;
}

__global__ void scatter_kernel(const int* __restrict__ ei, int* __restrict__ cursor,
                               int* __restrict__ srcs) {
    int e = blockIdx.x * 256 + threadIdx.x;
    if (e < EE) {
        int s = ei[e];
        int d = ei[EE + e];
        int pos = atomicAdd(&cursor[d], 1);
        srcs[pos] = s;
    }
}

// ---------------- fp32 -> fp16 convert (once, for x_in) ----------------

__global__ void cvt_kernel(const float* __restrict__ in, __half* __restrict__ out) {
    int i = blockIdx.x * 256 + threadIdx.x;  // one uint4 (8 halves) per thread
    if (i >= NN * 16) return;
    const float4* p = (const float4*)in + i * 2;
    float4 a = p[0], b = p[1];
    uint4 o;
    o.x = f2h(a.x, a.y);
    o.y = f2h(a.z, a.w);
    o.z = f2h(b.x, b.y);
    o.w = f2h(b.z, b.w);
    ((uint4*)out)[i] = o;
}

// ---------------- GIN aggregation over fp16 rows, prev-layer BN2+ReLU fused ----------
// wave = 1 node. lane = (g,l): g=lane>>3 edge slot, l=lane&7 dim chunk [l*16,l*16+16).
// Each lane: 2 dwordx4 loads (32B fp16) per edge; BN table in LDS swizzled [j*8+l].

template <bool BN>
__global__ __launch_bounds__(256) void agg_kernel(const __half* __restrict__ x,
                                                  const int* __restrict__ offs,
                                                  const int* __restrict__ srcs,
                                                  const float* __restrict__ epsp, int layer,
                                                  const float* __restrict__ stats,
                                                  const float* __restrict__ bg,
                                                  const float* __restrict__ bb,
                                                  float* __restrict__ h0) {
    __shared__ float lsb[256];
    if (BN) {
        if (threadIdx.x < 128) {
            int c = threadIdx.x;
            float mu = stats[c] * (1.0f / NN);
            float var = stats[128 + c] * (1.0f / NN) - mu * mu;
            float inv = rsqrtf(var + BNEPS);
            float sc = bg[c] * inv;
            int pos = (c & 15) * 8 + (c >> 4);  // swizzle: conflict-free reads
            lsb[pos] = sc;
            lsb[128 + pos] = bb[c] - mu * sc;
        }
        __syncthreads();
    }
    int node = blockIdx.x * 4 + (threadIdx.x >> 6);
    if (node >= NN) return;
    int lane = threadIdx.x & 63;
    int g = lane >> 3;
    int l = lane & 7;
    float sc[16], sh[16];
    if (BN) {
#pragma unroll
        for (int j = 0; j < 16; ++j) {
            sc[j] = lsb[j * 8 + l];
            sh[j] = lsb[128 + j * 8 + l];
        }
    }
    float acc[16];
#pragma unroll
    for (int j = 0; j < 16; ++j) acc[j] = 0.f;

    int beg = offs[node], end = offs[node + 1];
    int sI = (beg + g < end) ? srcs[beg + g] : 0;
    for (int base = beg; base + g < end; base += 8) {
        int sN = (base + 8 + g < end) ? srcs[base + 8 + g] : 0;
        const uint4* row = (const uint4*)(x + (size_t)sI * 128) + l * 2;
        uint4 va = row[0], vb = row[1];
        float2 f;
#pragma unroll
        for (int j = 0; j < 8; ++j) {
            unsigned int u = (j == 0) ? va.x : (j == 1) ? va.y : (j == 2) ? va.z
                             : (j == 3) ? va.w : (j == 4) ? vb.x : (j == 5) ? vb.y
                             : (j == 6) ? vb.z : vb.w;
            f = h2f(u);
            if (BN) {
                f.x = fmaxf(fmaf(f.x, sc[2 * j], sh[2 * j]), 0.f);
                f.y = fmaxf(fmaf(f.y, sc[2 * j + 1], sh[2 * j + 1]), 0.f);
            }
            acc[2 * j] += f.x;
            acc[2 * j + 1] += f.y;
        }
        sI = sN;
    }
    float e1 = 1.0f + epsp[layer];
    if (g == 0) {
        const uint4* row = (const uint4*)(x + (size_t)node * 128) + l * 2;
        uint4 va = row[0], vb = row[1];
        float2 f;
#pragma unroll
        for (int j = 0; j < 8; ++j) {
            unsigned int u = (j == 0) ? va.x : (j == 1) ? va.y : (j == 2) ? va.z
                             : (j == 3) ? va.w : (j == 4) ? vb.x : (j == 5) ? vb.y
                             : (j == 6) ? vb.z : vb.w;
            f = h2f(u);
            if (BN) {
                f.x = fmaxf(fmaf(f.x, sc[2 * j], sh[2 * j]), 0.f);
                f.y = fmaxf(fmaf(f.y, sc[2 * j + 1], sh[2 * j + 1]), 0.f);
            }
            acc[2 * j] = fmaf(e1, f.x, acc[2 * j]);
            acc[2 * j + 1] = fmaf(e1, f.y, acc[2 * j + 1]);
        }
    }
#pragma unroll
    for (int d = 8; d < 64; d <<= 1)
#pragma unroll
        for (int j = 0; j < 16; ++j) acc[j] += __shfl_xor(acc[j], d);
    if (g == 0) {
        float4* o = (float4*)(h0 + (size_t)node * 128 + l * 16);
#pragma unroll
        for (int j = 0; j < 4; ++j)
            o[j] = make_float4(acc[4 * j], acc[4 * j + 1], acc[4 * j + 2], acc[4 * j + 3]);
    }
}

// ---------------- GEMM1: y1 = h0 (Nx128) @ W (128x64); plain-atomic stats epilogue ------

__global__ __launch_bounds__(256) void gemm1_kernel(const float* __restrict__ h0,
                                                    const float* __restrict__ W,
                                                    float* __restrict__ y,
                                                    float* __restrict__ stats) {
    __shared__ float lW[128 * 64];
    for (int t = threadIdx.x; t < 2048; t += 256)
        ((float4*)lW)[t] = ((const float4*)W)[t];
    __syncthreads();
    int q = threadIdx.x & 3;
    int slot = threadIdx.x >> 2;
    int n0 = blockIdx.x * 256 + slot * 4;
    bool vld[4];
    const float4* xr[4];
#pragma unroll
    for (int r = 0; r < 4; ++r) {
        vld[r] = (n0 + r) < NN;
        xr[r] = (const float4*)(h0 + (size_t)(vld[r] ? n0 + r : 0) * 128);
    }
    float acc[4][16];
#pragma unroll
    for (int r = 0; r < 4; ++r)
#pragma unroll
        for (int j = 0; j < 16; ++j) acc[r][j] = 0.f;
    const float4 z4 = make_float4(0.f, 0.f, 0.f, 0.f);
#pragma unroll 2
    for (int k4 = 0; k4 < 32; ++k4) {
        float4 xv[4];
#pragma unroll
        for (int r = 0; r < 4; ++r) xv[r] = vld[r] ? xr[r][k4] : z4;
#pragma unroll
        for (int kk = 0; kk < 4; ++kk) {
            const float4* wr = (const float4*)(lW + (k4 * 4 + kk) * 64 + q * 16);
            float4 w0 = wr[0], w1 = wr[1], w2 = wr[2], w3 = wr[3];
#pragma unroll
            for (int r = 0; r < 4; ++r) {
                float a = (kk == 0) ? xv[r].x : (kk == 1) ? xv[r].y : (kk == 2) ? xv[r].z
                                                                                : xv[r].w;
                acc[r][0] = fmaf(a, w0.x, acc[r][0]);
                acc[r][1] = fmaf(a, w0.y, acc[r][1]);
                acc[r][2] = fmaf(a, w0.z, acc[r][2]);
                acc[r][3] = fmaf(a, w0.w, acc[r][3]);
                acc[r][4] = fmaf(a, w1.x, acc[r][4]);
                acc[r][5] = fmaf(a, w1.y, acc[r][5]);
                acc[r][6] = fmaf(a, w1.z, acc[r][6]);
                acc[r][7] = fmaf(a, w1.w, acc[r][7]);
                acc[r][8] = fmaf(a, w2.x, acc[r][8]);
                acc[r][9] = fmaf(a, w2.y, acc[r][9]);
                acc[r][10] = fmaf(a, w2.z, acc[r][10]);
                acc[r][11] = fmaf(a, w2.w, acc[r][11]);
                acc[r][12] = fmaf(a, w3.x, acc[r][12]);
                acc[r][13] = fmaf(a, w3.y, acc[r][13]);
                acc[r][14] = fmaf(a, w3.z, acc[r][14]);
                acc[r][15] = fmaf(a, w3.w, acc[r][15]);
            }
        }
    }
#pragma unroll
    for (int r = 0; r < 4; ++r) {
        if (vld[r]) {
            float4* yr = (float4*)(y + (size_t)(n0 + r) * 64 + q * 16);
#pragma unroll
            for (int j = 0; j < 4; ++j)
                yr[j] = make_float4(acc[r][4 * j], acc[r][4 * j + 1], acc[r][4 * j + 2],
                                    acc[r][4 * j + 3]);
        }
    }
    float s[16], s2[16];
#pragma unroll
    for (int j = 0; j < 16; ++j) {
        s[j] = acc[0][j] + acc[1][j] + acc[2][j] + acc[3][j];
        s2[j] = acc[0][j] * acc[0][j] + acc[1][j] * acc[1][j] + acc[2][j] * acc[2][j] +
                acc[3][j] * acc[3][j];
    }
#pragma unroll
    for (int d = 4; d < 64; d <<= 1)
#pragma unroll
        for (int j = 0; j < 16; ++j) {
            s[j] += __shfl_xor(s[j], d);
            s2[j] += __shfl_xor(s2[j], d);
        }
    __shared__ float lst[4][128];
    int wv = threadIdx.x >> 6, ln = threadIdx.x & 63;
    if (ln < 4) {
#pragma unroll
        for (int j = 0; j < 16; ++j) {
            lst[wv][ln * 16 + j] = s[j];
            lst[wv][64 + ln * 16 + j] = s2[j];
        }
    }
    __syncthreads();
    if (threadIdx.x < 128)
        atomicAdd(&stats[threadIdx.x], lst[0][threadIdx.x] + lst[1][threadIdx.x] +
                                           lst[2][threadIdx.x] + lst[3][threadIdx.x]);
}

// ---------------- GEMM2: y2 = relu(bn1(y1)) (Nx64) @ W (64x128) -> fp16; stats --------

__global__ __launch_bounds__(256) void gemm2_kernel(const float* __restrict__ y1,
                                                    const float* __restrict__ W,
                                                    const float* __restrict__ stats1,
                                                    const float* __restrict__ bg,
                                                    const float* __restrict__ bb,
                                                    __half* __restrict__ y2h,
                                                    float* __restrict__ stats2) {
    __shared__ float lW[64 * 128];
    __shared__ float lsb[128];
    for (int t = threadIdx.x; t < 2048; t += 256)
        ((float4*)lW)[t] = ((const float4*)W)[t];
    if (threadIdx.x < 64) {
        int c = threadIdx.x;
        float mu = stats1[c] * (1.0f / NN);
        float var = stats1[64 + c] * (1.0f / NN) - mu * mu;
        float inv = rsqrtf(var + BNEPS);
        float sc = bg[c] * inv;
        lsb[c] = sc;
        lsb[64 + c] = bb[c] - mu * sc;
    }
    __syncthreads();
    int q = threadIdx.x & 7;
    int slot = threadIdx.x >> 3;
    int n0 = blockIdx.x * 128 + slot * 4;
    bool vld[4];
    const float4* xr[4];
#pragma unroll
    for (int r = 0; r < 4; ++r) {
        vld[r] = (n0 + r) < NN;
        xr[r] = (const float4*)(y1 + (size_t)(vld[r] ? n0 + r : 0) * 64);
    }
    float acc[4][16];
#pragma unroll
    for (int r = 0; r < 4; ++r)
#pragma unroll
        for (int j = 0; j < 16; ++j) acc[r][j] = 0.f;
    const float4 z4 = make_float4(0.f, 0.f, 0.f, 0.f);
#pragma unroll 2
    for (int k4 = 0; k4 < 16; ++k4) {
        float4 xv[4];
#pragma unroll
        for (int r = 0; r < 4; ++r) xv[r] = vld[r] ? xr[r][k4] : z4;
#pragma unroll
        for (int kk = 0; kk < 4; ++kk) {
            int k = k4 * 4 + kk;
            float sck = lsb[k], shk = lsb[64 + k];
            const float4* wr = (const float4*)(lW + k * 128 + q * 16);
            float4 w0 = wr[0], w1 = wr[1], w2 = wr[2], w3 = wr[3];
#pragma unroll
            for (int r = 0; r < 4; ++r) {
                float raw = (kk == 0) ? xv[r].x : (kk == 1) ? xv[r].y : (kk == 2) ? xv[r].z
                                                                                  : xv[r].w;
                float a = fmaxf(fmaf(raw, sck, shk), 0.f);
                acc[r][0] = fmaf(a, w0.x, acc[r][0]);
                acc[r][1] = fmaf(a, w0.y, acc[r][1]);
                acc[r][2] = fmaf(a, w0.z, acc[r][2]);
                acc[r][3] = fmaf(a, w0.w, acc[r][3]);
                acc[r][4] = fmaf(a, w1.x, acc[r][4]);
                acc[r][5] = fmaf(a, w1.y, acc[r][5]);
                acc[r][6] = fmaf(a, w1.z, acc[r][6]);
                acc[r][7] = fmaf(a, w1.w, acc[r][7]);
                acc[r][8] = fmaf(a, w2.x, acc[r][8]);
                acc[r][9] = fmaf(a, w2.y, acc[r][9]);
                acc[r][10] = fmaf(a, w2.z, acc[r][10]);
                acc[r][11] = fmaf(a, w2.w, acc[r][11]);
                acc[r][12] = fmaf(a, w3.x, acc[r][12]);
                acc[r][13] = fmaf(a, w3.y, acc[r][13]);
                acc[r][14] = fmaf(a, w3.z, acc[r][14]);
                acc[r][15] = fmaf(a, w3.w, acc[r][15]);
            }
        }
    }
#pragma unroll
    for (int r = 0; r < 4; ++r) {
        if (vld[r]) {
            uint4 o0, o1;
            o0.x = f2h(acc[r][0], acc[r][1]);
            o0.y = f2h(acc[r][2], acc[r][3]);
            o0.z = f2h(acc[r][4], acc[r][5]);
            o0.w = f2h(acc[r][6], acc[r][7]);
            o1.x = f2h(acc[r][8], acc[r][9]);
            o1.y = f2h(acc[r][10], acc[r][11]);
            o1.z = f2h(acc[r][12], acc[r][13]);
            o1.w = f2h(acc[r][14], acc[r][15]);
            uint4* yr = (uint4*)(y2h + (size_t)(n0 + r) * 128 + q * 16);
            yr[0] = o0;
            yr[1] = o1;
        }
    }
    float s[16], s2[16];
#pragma unroll
    for (int j = 0; j < 16; ++j) {
        s[j] = acc[0][j] + acc[1][j] + acc[2][j] + acc[3][j];
        s2[j] = acc[0][j] * acc[0][j] + acc[1][j] * acc[1][j] + acc[2][j] * acc[2][j] +
                acc[3][j] * acc[3][j];
    }
#pragma unroll
    for (int d = 8; d < 64; d <<= 1)
#pragma unroll
        for (int j = 0; j < 16; ++j) {
            s[j] += __shfl_xor(s[j], d);
            s2[j] += __shfl_xor(s2[j], d);
        }
    __shared__ float lst[4][256];
    int wv = threadIdx.x >> 6, ln = threadIdx.x & 63;
    if (ln < 8) {
#pragma unroll
        for (int j = 0; j < 16; ++j) {
            lst[wv][ln * 16 + j] = s[j];
            lst[wv][128 + ln * 16 + j] = s2[j];
        }
    }
    __syncthreads();
    atomicAdd(&stats2[threadIdx.x], lst[0][threadIdx.x] + lst[1][threadIdx.x] +
                                        lst[2][threadIdx.x] + lst[3][threadIdx.x]);
}

// ---------------- last layer: x = relu( relu(bn1(y1)) @ Wlast (64x2) ) ----------------

__global__ void gemm_last_kernel(const float* __restrict__ y1, const float* __restrict__ W,
                                 const float* __restrict__ stats1,
                                 const float* __restrict__ bg, const float* __restrict__ bb,
                                 float* __restrict__ xl) {
    __shared__ float lw[128];
    __shared__ float lsb[128];
    if (threadIdx.x < 128) lw[threadIdx.x] = W[threadIdx.x];
    if (threadIdx.x < 64) {
        int c = threadIdx.x;
        float mu = stats1[c] * (1.0f / NN);
        float var = stats1[64 + c] * (1.0f / NN) - mu * mu;
        float inv = rsqrtf(var + BNEPS);
        float sc = bg[c] * inv;
        lsb[c] = sc;
        lsb[64 + c] = bb[c] - mu * sc;
    }
    __syncthreads();
    int n = blockIdx.x * 256 + threadIdx.x;
    if (n >= NN) return;
    float a0 = 0.f, a1 = 0.f;
    const float* row = y1 + (size_t)n * 64;
#pragma unroll
    for (int k = 0; k < 64; ++k) {
        float v = fmaxf(fmaf(row[k], lsb[k], lsb[64 + k]), 0.f);
        a0 = fmaf(v, lw[2 * k + 0], a0);
        a1 = fmaf(v, lw[2 * k + 1], a1);
    }
    xl[2 * n + 0] = fmaxf(a0, 0.f);
    xl[2 * n + 1] = fmaxf(a1, 0.f);
}

// ---------------- mean pool over sorted batch via wave-segmented scan ----------------

__global__ void pool_accum_kernel(const float* __restrict__ xl, const int* __restrict__ batch,
                                  float* __restrict__ pool) {
    int n = blockIdx.x * 256 + threadIdx.x;
    int lane = threadIdx.x & 63;
    int g = -1;
    float v0 = 0.f, v1 = 0.f, c = 0.f;
    if (n < NN) {
        g = batch[n];
        v0 = xl[2 * n + 0];
        v1 = xl[2 * n + 1];
        c = 1.0f;
    }
    for (int d = 1; d < 64; d <<= 1) {
        int tg = __shfl_up(g, d);
        float t0 = __shfl_up(v0, d);
        float t1 = __shfl_up(v1, d);
        float tc = __shfl_up(c, d);
        if (lane >= d && tg == g) { v0 += t0; v1 += t1; c += tc; }
    }
    int gn = __shfl_down(g, 1);
    bool lastv = (lane == 63) || (gn != g);
    if (g >= 0 && lastv) {
        atomicAdd(&pool[g * 3 + 0], v0);
        atomicAdd(&pool[g * 3 + 1], v1);
        atomicAdd(&pool[g * 3 + 2], c);
    }
}

__global__ void pool_fin_kernel(const float* __restrict__ pool, float* __restrict__ out) {
    int t = threadIdx.x;
    if (t < GG * 2) {
        int g = t >> 1, j = t & 1;
        float cnt = pool[g * 3 + 2];
        out[t] = pool[g * 3 + j] / fmaxf(cnt, 1.0f);
    }
}

// ---------------- launch ----------------

extern "C" void kernel_launch(void* const* d_in, const int* in_sizes, int n_in,
                              void* d_out, int out_size, void* d_ws, size_t ws_size,
                              hipStream_t stream) {
    const float* x_in  = (const float*)d_in[0];
    const int*   ei    = (const int*)d_in[1];
    const int*   batch = (const int*)d_in[3];
    const float* W1    = (const float*)d_in[4];
    const float* bn1g  = (const float*)d_in[5];
    const float* bn1b  = (const float*)d_in[6];
    const float* W2    = (const float*)d_in[7];
    const float* bn2g  = (const float*)d_in[8];
    const float* bn2b  = (const float*)d_in[9];
    const float* Wlast = (const float*)d_in[10];
    const float* eps   = (const float*)d_in[11];
    float* out = (float*)d_out;

    char* ws = (char*)d_ws;
    size_t off = 0;
    auto alloc = [&](size_t bytes) -> char* {
        char* p = ws + off;
        off += (bytes + 255) & ~(size_t)255;
        return p;
    };
    // -- zeroed region first (one memset) --
    int*   deg      = (int*)alloc((size_t)NN * 4);
    float* statsall = (float*)alloc(16 * 256 * 4);  // slot s: [0..C) sum, [C..2C) sumsq
    float* pool     = (float*)alloc((size_t)GG * 3 * 4);
    size_t zero_len = off;
    // -- rest --
    int*    offs   = (int*)alloc((size_t)(NN + 1) * 4);
    int*    cursor = (int*)alloc((size_t)NN * 4);
    int*    bsum   = (int*)alloc(64 * 4);
    int*    srcs   = (int*)alloc((size_t)EE * 4);
    __half* X16    = (__half*)alloc((size_t)NN * 128 * 2);  // fp16 x_in
    __half* A16    = (__half*)alloc((size_t)NN * 128 * 2);  // fp16 raw y2
    float*  B      = (float*)alloc((size_t)NN * 128 * 4);   // h0
    float*  Cb     = (float*)alloc((size_t)NN * 64 * 4);    // raw y1
    float*  xlast  = (float*)alloc((size_t)NN * 2 * 4);
    (void)ws_size; (void)n_in; (void)in_sizes; (void)out_size;

    hipMemsetAsync(ws, 0, zero_len, stream);

    // CSR build (by dst)
    hist_kernel<<<(EE + 255) / 256, 256, 0, stream>>>(ei, deg);
    scan1_kernel<<<49, 1024, 0, stream>>>(deg, offs, bsum);
    scan3_kernel<<<49, 1024, 0, stream>>>(offs, cursor, bsum);
    scatter_kernel<<<(EE + 255) / 256, 256, 0, stream>>>(ei, cursor, srcs);
    cvt_kernel<<<(NN * 16 + 255) / 256, 256, 0, stream>>>(x_in, X16);

    const int GB1 = (NN + 255) / 256;  // 196
    const int GB2 = (NN + 127) / 128;  // 391

    for (int i = 0; i < 7; ++i) {
        int s1 = 2 * i, s2 = 2 * i + 1;
        if (i == 0) {
            agg_kernel<false><<<(NN + 3) / 4, 256, 0, stream>>>(X16, offs, srcs, eps, i,
                                                                nullptr, nullptr, nullptr, B);
        } else {
            agg_kernel<true><<<(NN + 3) / 4, 256, 0, stream>>>(
                A16, offs, srcs, eps, i, statsall + (2 * i - 1) * 256, bn2g + (i - 1) * 128,
                bn2b + (i - 1) * 128, B);
        }
        gemm1_kernel<<<GB1, 256, 0, stream>>>(B, W1 + (size_t)i * 128 * 64, Cb,
                                              statsall + s1 * 256);
        if (i < 6) {
            gemm2_kernel<<<GB2, 256, 0, stream>>>(Cb, W2 + (size_t)i * 64 * 128,
                                                  statsall + s1 * 256, bn1g + i * 64,
                                                  bn1b + i * 64, A16, statsall + s2 * 256);
        } else {
            gemm_last_kernel<<<(NN + 255) / 256, 256, 0, stream>>>(
                Cb, Wlast, statsall + s1 * 256, bn1g + i * 64, bn1b + i * 64, xlast);
        }
    }

    pool_accum_kernel<<<(NN + 255) / 256, 256, 0, stream>>>(xlast, batch, pool);
    pool_fin_kernel<<<1, 128, 0, stream>>>(pool, out);
}

// Round 6
// 772.265 us; speedup vs baseline: 2.4631x; 1.0851x over previous
//
#include <hip/hip_runtime.h>
#include <hip/hip_fp16.h>

#define NN 50000
#define EE 800000
#define GG 64
#define BNEPS 1e-5f

typedef _Float16 f16x8 __attribute__((ext_vector_type(8)));
typedef float f32x4 __attribute__((ext_vector_type(4)));

__device__ inline float2 h2f(unsigned int u) {
    __half2 h = __builtin_bit_cast(__half2, u);
    return __half22float2(h);
}
__device__ inline unsigned int f2h(float a, float b) {
    __half2 h = __float22half2_rn(make_float2(a, b));
    return __builtin_bit_cast(unsigned int, h);
}
__device__ inline f16x8 zf16() {
    f16x8 v;
#pragma unroll
    for (int i = 0; i < 8; ++i) v[i] = (_Float16)0.f;
    return v;
}

// ---------------- CSR build ----------------

__global__ void hist_kernel(const int* __restrict__ ei, int* __restrict__ deg) {
    int e = blockIdx.x * 256 + threadIdx.x;
    if (e < EE) atomicAdd(&deg[ei[EE + e]], 1);
}

__global__ void scan1_kernel(const int* __restrict__ deg, int* __restrict__ offs,
                             int* __restrict__ bsum) {
    __shared__ int lds[1024];
    int i = blockIdx.x * 1024 + threadIdx.x;
    int v = (i < NN) ? deg[i] : 0;
    lds[threadIdx.x] = v;
    __syncthreads();
    for (int d = 1; d < 1024; d <<= 1) {
        int t = (threadIdx.x >= d) ? lds[threadIdx.x - d] : 0;
        __syncthreads();
        lds[threadIdx.x] += t;
        __syncthreads();
    }
    int incl = lds[threadIdx.x];
    if (i < NN) offs[i] = incl - v;
    if (threadIdx.x == 1023) bsum[blockIdx.x] = incl;
}

__global__ void scan3_kernel(int* __restrict__ offs, int* __restrict__ cursor,
                             const int* __restrict__ bsum) {
    __shared__ int base;
    if (threadIdx.x == 0) {
        int r = 0;
        for (int b = 0; b < (int)blockIdx.x; ++b) r += bsum[b];
        base = r;
    }
    __syncthreads();
    int i = blockIdx.x * 1024 + threadIdx.x;
    if (i < NN) {
        int o = offs[i] + base;
        offs[i] = o;
        cursor[i] = o;
    }
    if (i == 0 && blockIdx.x == 0) offs[NN] = EE;
}

__global__ void scatter_kernel(const int* __restrict__ ei, int* __restrict__ cursor,
                               int* __restrict__ srcs) {
    int e = blockIdx.x * 256 + threadIdx.x;
    if (e < EE) {
        int s = ei[e];
        int d = ei[EE + e];
        int pos = atomicAdd(&cursor[d], 1);
        srcs[pos] = s;
    }
}

// ---------------- fp32 -> fp16 convert (once, for x_in) ----------------

__global__ void cvt_kernel(const float* __restrict__ in, __half* __restrict__ out) {
    int i = blockIdx.x * 256 + threadIdx.x;
    if (i >= NN * 16) return;
    const float4* p = (const float4*)in + i * 2;
    float4 a = p[0], b = p[1];
    uint4 o;
    o.x = f2h(a.x, a.y);
    o.y = f2h(a.z, a.w);
    o.z = f2h(b.x, b.y);
    o.w = f2h(b.z, b.w);
    ((uint4*)out)[i] = o;
}

// ---------------- pack W[K][C] fp32 into mfma 16x16x32 B-fragment fp16 layout ---------
// Wpk[layer][(kf*NCF+cf)*64 + lane][j] = W[kf*32 + (lane>>4)*8 + j][cf*16 + (lane&15)]

__global__ void packW_kernel(const float* __restrict__ W, __half* __restrict__ Wpk, int K,
                             int C, int layers) {
    int NKF = K / 32, NCF = C / 16;
    int per_layer = NKF * NCF * 64;
    int t = blockIdx.x * 256 + threadIdx.x;
    if (t >= layers * per_layer) return;
    int layer = t / per_layer, r = t % per_layer;
    int kf = r / (NCF * 64), r2 = r % (NCF * 64);
    int cf = r2 >> 6, l = r2 & 63;
    const float* Wl = W + (size_t)layer * K * C;
    __half* o = Wpk + ((size_t)layer * per_layer + ((size_t)(kf * NCF + cf) * 64 + l)) * 8;
    int k0 = kf * 32 + (l >> 4) * 8, c = cf * 16 + (l & 15);
#pragma unroll
    for (int j = 0; j < 8; ++j) o[j] = __float2half(Wl[(size_t)(k0 + j) * C + c]);
}

// ---------------- GIN aggregation over fp16 rows, prev-layer BN2+ReLU fused ----------
// wave = 1 node. lane = (g,l): g=lane>>3 edge slot, l=lane&7 dim chunk [l*16,l*16+16).

template <bool BN>
__global__ __launch_bounds__(256) void agg_kernel(const __half* __restrict__ x,
                                                  const int* __restrict__ offs,
                                                  const int* __restrict__ srcs,
                                                  const float* __restrict__ epsp, int layer,
                                                  const float* __restrict__ stats,
                                                  const float* __restrict__ bg,
                                                  const float* __restrict__ bb,
                                                  __half* __restrict__ h0) {
    __shared__ float lsb[256];
    if (BN) {
        if (threadIdx.x < 128) {
            int c = threadIdx.x;
            float mu = stats[c] * (1.0f / NN);
            float var = stats[128 + c] * (1.0f / NN) - mu * mu;
            float inv = rsqrtf(var + BNEPS);
            float sc = bg[c] * inv;
            int pos = (c & 15) * 8 + (c >> 4);  // swizzle: conflict-free reads
            lsb[pos] = sc;
            lsb[128 + pos] = bb[c] - mu * sc;
        }
        __syncthreads();
    }
    int node = blockIdx.x * 4 + (threadIdx.x >> 6);
    if (node >= NN) return;
    int lane = threadIdx.x & 63;
    int g = lane >> 3;
    int l = lane & 7;
    float sc[16], sh[16];
    if (BN) {
#pragma unroll
        for (int j = 0; j < 16; ++j) {
            sc[j] = lsb[j * 8 + l];
            sh[j] = lsb[128 + j * 8 + l];
        }
    }
    float acc[16];
#pragma unroll
    for (int j = 0; j < 16; ++j) acc[j] = 0.f;

    int beg = offs[node], end = offs[node + 1];
    int sI = (beg + g < end) ? srcs[beg + g] : 0;
    for (int base = beg; base + g < end; base += 8) {
        int sN = (base + 8 + g < end) ? srcs[base + 8 + g] : 0;
        const uint4* row = (const uint4*)(x + (size_t)sI * 128) + l * 2;
        uint4 va = row[0], vb = row[1];
        float2 f;
#pragma unroll
        for (int j = 0; j < 8; ++j) {
            unsigned int u = (j == 0) ? va.x : (j == 1) ? va.y : (j == 2) ? va.z
                             : (j == 3) ? va.w : (j == 4) ? vb.x : (j == 5) ? vb.y
                             : (j == 6) ? vb.z : vb.w;
            f = h2f(u);
            if (BN) {
                f.x = fmaxf(fmaf(f.x, sc[2 * j], sh[2 * j]), 0.f);
                f.y = fmaxf(fmaf(f.y, sc[2 * j + 1], sh[2 * j + 1]), 0.f);
            }
            acc[2 * j] += f.x;
            acc[2 * j + 1] += f.y;
        }
        sI = sN;
    }
    float e1 = 1.0f + epsp[layer];
    if (g == 0) {
        const uint4* row = (const uint4*)(x + (size_t)node * 128) + l * 2;
        uint4 va = row[0], vb = row[1];
        float2 f;
#pragma unroll
        for (int j = 0; j < 8; ++j) {
            unsigned int u = (j == 0) ? va.x : (j == 1) ? va.y : (j == 2) ? va.z
                             : (j == 3) ? va.w : (j == 4) ? vb.x : (j == 5) ? vb.y
                             : (j == 6) ? vb.z : vb.w;
            f = h2f(u);
            if (BN) {
                f.x = fmaxf(fmaf(f.x, sc[2 * j], sh[2 * j]), 0.f);
                f.y = fmaxf(fmaf(f.y, sc[2 * j + 1], sh[2 * j + 1]), 0.f);
            }
            acc[2 * j] = fmaf(e1, f.x, acc[2 * j]);
            acc[2 * j + 1] = fmaf(e1, f.y, acc[2 * j + 1]);
        }
    }
#pragma unroll
    for (int d = 8; d < 64; d <<= 1)
#pragma unroll
        for (int j = 0; j < 16; ++j) acc[j] += __shfl_xor(acc[j], d);
    if (g == 0) {
        uint4 o0, o1;
        o0.x = f2h(acc[0], acc[1]);
        o0.y = f2h(acc[2], acc[3]);
        o0.z = f2h(acc[4], acc[5]);
        o0.w = f2h(acc[6], acc[7]);
        o1.x = f2h(acc[8], acc[9]);
        o1.y = f2h(acc[10], acc[11]);
        o1.z = f2h(acc[12], acc[13]);
        o1.w = f2h(acc[14], acc[15]);
        uint4* o = (uint4*)(h0 + (size_t)node * 128 + l * 16);
        o[0] = o0;
        o[1] = o1;
    }
}

// ---------------- GEMM1 (MFMA): y1 = h0 (Nx128 fp16) @ W1 (128x64) -> fp16 + stats ------
// wave = 16 nodes x 64 ch. 4 k-frags x 4 ch-frags, fp32 accum, stats from registers.

__global__ __launch_bounds__(256) void gemm1_kernel(const __half* __restrict__ h0,
                                                    const __half* __restrict__ Wpk,
                                                    __half* __restrict__ y,
                                                    float* __restrict__ stats) {
    int lane = threadIdx.x & 63, wave = threadIdx.x >> 6, g = lane >> 4;
    f16x8 bf[4][4];
    const f16x8* wp = (const f16x8*)Wpk;
#pragma unroll
    for (int kf = 0; kf < 4; ++kf)
#pragma unroll
        for (int cf = 0; cf < 4; ++cf) bf[kf][cf] = wp[(kf * 4 + cf) * 64 + lane];
    int node16 = (blockIdx.x * 4 + wave) * 16;
    bool wv = node16 < NN;  // NN % 16 == 0: waves are all-or-nothing
    f32x4 acc[4];
#pragma unroll
    for (int cf = 0; cf < 4; ++cf) acc[cf] = (f32x4){0.f, 0.f, 0.f, 0.f};
    const f16x8* xr = (const f16x8*)(h0 + (size_t)(node16 + (lane & 15)) * 128);
#pragma unroll
    for (int kf = 0; kf < 4; ++kf) {
        f16x8 af = wv ? xr[kf * 4 + g] : zf16();
#pragma unroll
        for (int cf = 0; cf < 4; ++cf)
            acc[cf] = __builtin_amdgcn_mfma_f32_16x16x32_f16(af, bf[kf][cf], acc[cf], 0, 0, 0);
    }
    // store fp16 (pair even/odd lanes -> 4B stores)
#pragma unroll
    for (int cf = 0; cf < 4; ++cf) {
#pragma unroll
        for (int r = 0; r < 4; ++r) {
            float v = acc[cf][r];
            float p = __shfl_xor(v, 1);
            if (wv && !(lane & 1)) {
                int node = node16 + g * 4 + r;
                int ch = cf * 16 + (lane & 15);
                *(unsigned int*)(y + (size_t)node * 64 + ch) = f2h(v, p);
            }
        }
    }
    // stats
    float s[4], s2[4];
#pragma unroll
    for (int cf = 0; cf < 4; ++cf) {
        float a = 0.f, b = 0.f;
#pragma unroll
        for (int r = 0; r < 4; ++r) {
            float v = wv ? acc[cf][r] : 0.f;
            a += v;
            b += v * v;
        }
        s[cf] = a;
        s2[cf] = b;
    }
#pragma unroll
    for (int d = 16; d < 64; d <<= 1)
#pragma unroll
        for (int cf = 0; cf < 4; ++cf) {
            s[cf] += __shfl_xor(s[cf], d);
            s2[cf] += __shfl_xor(s2[cf], d);
        }
    __shared__ float lst[4][128];
    if (lane < 16) {
#pragma unroll
        for (int cf = 0; cf < 4; ++cf) {
            lst[wave][cf * 16 + lane] = s[cf];
            lst[wave][64 + cf * 16 + lane] = s2[cf];
        }
    }
    __syncthreads();
    if (threadIdx.x < 128)
        atomicAdd(&stats[threadIdx.x], lst[0][threadIdx.x] + lst[1][threadIdx.x] +
                                           lst[2][threadIdx.x] + lst[3][threadIdx.x]);
}

// ---------------- GEMM2 (MFMA): y2 = relu(bn1(y1)) (Nx64) @ W2 (64x128) -> fp16 + stats --

__global__ __launch_bounds__(256) void gemm2_kernel(const __half* __restrict__ y1,
                                                    const __half* __restrict__ Wpk,
                                                    const float* __restrict__ stats1,
                                                    const float* __restrict__ bg,
                                                    const float* __restrict__ bb,
                                                    __half* __restrict__ y2,
                                                    float* __restrict__ stats2) {
    __shared__ float lsc[64], lsh[64];
    if (threadIdx.x < 64) {
        int c = threadIdx.x;
        float mu = stats1[c] * (1.0f / NN);
        float var = stats1[64 + c] * (1.0f / NN) - mu * mu;
        float inv = rsqrtf(var + BNEPS);
        float sc = bg[c] * inv;
        lsc[c] = sc;
        lsh[c] = bb[c] - mu * sc;
    }
    __syncthreads();
    int lane = threadIdx.x & 63, wave = threadIdx.x >> 6, g = lane >> 4;
    f16x8 bf[2][8];
    const f16x8* wp = (const f16x8*)Wpk;
#pragma unroll
    for (int kf = 0; kf < 2; ++kf)
#pragma unroll
        for (int cf = 0; cf < 8; ++cf) bf[kf][cf] = wp[(kf * 8 + cf) * 64 + lane];
    int node16 = (blockIdx.x * 4 + wave) * 16;
    bool wv = node16 < NN;
    f32x4 acc[8];
#pragma unroll
    for (int cf = 0; cf < 8; ++cf) acc[cf] = (f32x4){0.f, 0.f, 0.f, 0.f};
    const f16x8* xr = (const f16x8*)(y1 + (size_t)(node16 + (lane & 15)) * 64);
#pragma unroll
    for (int kf = 0; kf < 2; ++kf) {
        f16x8 af = zf16();
        if (wv) {
            f16x8 raw = xr[kf * 4 + g];
            int k0 = kf * 32 + g * 8;
            float4 sc0 = *(const float4*)(lsc + k0);
            float4 sc1 = *(const float4*)(lsc + k0 + 4);
            float4 sh0 = *(const float4*)(lsh + k0);
            float4 sh1 = *(const float4*)(lsh + k0 + 4);
            af[0] = (_Float16)fmaxf(fmaf((float)raw[0], sc0.x, sh0.x), 0.f);
            af[1] = (_Float16)fmaxf(fmaf((float)raw[1], sc0.y, sh0.y), 0.f);
            af[2] = (_Float16)fmaxf(fmaf((float)raw[2], sc0.z, sh0.z), 0.f);
            af[3] = (_Float16)fmaxf(fmaf((float)raw[3], sc0.w, sh0.w), 0.f);
            af[4] = (_Float16)fmaxf(fmaf((float)raw[4], sc1.x, sh1.x), 0.f);
            af[5] = (_Float16)fmaxf(fmaf((float)raw[5], sc1.y, sh1.y), 0.f);
            af[6] = (_Float16)fmaxf(fmaf((float)raw[6], sc1.z, sh1.z), 0.f);
            af[7] = (_Float16)fmaxf(fmaf((float)raw[7], sc1.w, sh1.w), 0.f);
        }
#pragma unroll
        for (int cf = 0; cf < 8; ++cf)
            acc[cf] = __builtin_amdgcn_mfma_f32_16x16x32_f16(af, bf[kf][cf], acc[cf], 0, 0, 0);
    }
#pragma unroll
    for (int cf = 0; cf < 8; ++cf) {
#pragma unroll
        for (int r = 0; r < 4; ++r) {
            float v = acc[cf][r];
            float p = __shfl_xor(v, 1);
            if (wv && !(lane & 1)) {
                int node = node16 + g * 4 + r;
                int ch = cf * 16 + (lane & 15);
                *(unsigned int*)(y2 + (size_t)node * 128 + ch) = f2h(v, p);
            }
        }
    }
    float s[8], s2[8];
#pragma unroll
    for (int cf = 0; cf < 8; ++cf) {
        float a = 0.f, b = 0.f;
#pragma unroll
        for (int r = 0; r < 4; ++r) {
            float v = wv ? acc[cf][r] : 0.f;
            a += v;
            b += v * v;
        }
        s[cf] = a;
        s2[cf] = b;
    }
#pragma unroll
    for (int d = 16; d < 64; d <<= 1)
#pragma unroll
        for (int cf = 0; cf < 8; ++cf) {
            s[cf] += __shfl_xor(s[cf], d);
            s2[cf] += __shfl_xor(s2[cf], d);
        }
    __shared__ float lst[4][256];
    if (lane < 16) {
#pragma unroll
        for (int cf = 0; cf < 8; ++cf) {
            lst[wave][cf * 16 + lane] = s[cf];
            lst[wave][128 + cf * 16 + lane] = s2[cf];
        }
    }
    __syncthreads();
    atomicAdd(&stats2[threadIdx.x], lst[0][threadIdx.x] + lst[1][threadIdx.x] +
                                        lst[2][threadIdx.x] + lst[3][threadIdx.x]);
}

// ---------------- last layer: x = relu( relu(bn1(y1)) @ Wlast (64x2) ) ----------------

__global__ void gemm_last_kernel(const __half* __restrict__ y1, const float* __restrict__ W,
                                 const float* __restrict__ stats1,
                                 const float* __restrict__ bg, const float* __restrict__ bb,
                                 float* __restrict__ xl) {
    __shared__ float lw[128];
    __shared__ float lsc[64], lsh[64];
    if (threadIdx.x < 128) lw[threadIdx.x] = W[threadIdx.x];
    if (threadIdx.x < 64) {
        int c = threadIdx.x;
        float mu = stats1[c] * (1.0f / NN);
        float var = stats1[64 + c] * (1.0f / NN) - mu * mu;
        float inv = rsqrtf(var + BNEPS);
        float sc = bg[c] * inv;
        lsc[c] = sc;
        lsh[c] = bb[c] - mu * sc;
    }
    __syncthreads();
    int n = blockIdx.x * 256 + threadIdx.x;
    if (n >= NN) return;
    float a0 = 0.f, a1 = 0.f;
    const uint4* row = (const uint4*)(y1 + (size_t)n * 64);
#pragma unroll
    for (int c8 = 0; c8 < 8; ++c8) {
        uint4 u = row[c8];
#pragma unroll
        for (int j = 0; j < 4; ++j) {
            unsigned int w = (j == 0) ? u.x : (j == 1) ? u.y : (j == 2) ? u.z : u.w;
            float2 f = h2f(w);
            int k = c8 * 8 + j * 2;
            float v0 = fmaxf(fmaf(f.x, lsc[k], lsh[k]), 0.f);
            float v1 = fmaxf(fmaf(f.y, lsc[k + 1], lsh[k + 1]), 0.f);
            a0 = fmaf(v0, lw[2 * k + 0], a0);
            a1 = fmaf(v0, lw[2 * k + 1], a1);
            a0 = fmaf(v1, lw[2 * k + 2], a0);
            a1 = fmaf(v1, lw[2 * k + 3], a1);
        }
    }
    xl[2 * n + 0] = fmaxf(a0, 0.f);
    xl[2 * n + 1] = fmaxf(a1, 0.f);
}

// ---------------- mean pool over sorted batch via wave-segmented scan ----------------

__global__ void pool_accum_kernel(const float* __restrict__ xl, const int* __restrict__ batch,
                                  float* __restrict__ pool) {
    int n = blockIdx.x * 256 + threadIdx.x;
    int lane = threadIdx.x & 63;
    int g = -1;
    float v0 = 0.f, v1 = 0.f, c = 0.f;
    if (n < NN) {
        g = batch[n];
        v0 = xl[2 * n + 0];
        v1 = xl[2 * n + 1];
        c = 1.0f;
    }
    for (int d = 1; d < 64; d <<= 1) {
        int tg = __shfl_up(g, d);
        float t0 = __shfl_up(v0, d);
        float t1 = __shfl_up(v1, d);
        float tc = __shfl_up(c, d);
        if (lane >= d && tg == g) { v0 += t0; v1 += t1; c += tc; }
    }
    int gn = __shfl_down(g, 1);
    bool lastv = (lane == 63) || (gn != g);
    if (g >= 0 && lastv) {
        atomicAdd(&pool[g * 3 + 0], v0);
        atomicAdd(&pool[g * 3 + 1], v1);
        atomicAdd(&pool[g * 3 + 2], c);
    }
}

__global__ void pool_fin_kernel(const float* __restrict__ pool, float* __restrict__ out) {
    int t = threadIdx.x;
    if (t < GG * 2) {
        int g = t >> 1, j = t & 1;
        float cnt = pool[g * 3 + 2];
        out[t] = pool[g * 3 + j] / fmaxf(cnt, 1.0f);
    }
}

// ---------------- launch ----------------

extern "C" void kernel_launch(void* const* d_in, const int* in_sizes, int n_in,
                              void* d_out, int out_size, void* d_ws, size_t ws_size,
                              hipStream_t stream) {
    const float* x_in  = (const float*)d_in[0];
    const int*   ei    = (const int*)d_in[1];
    const int*   batch = (const int*)d_in[3];
    const float* W1    = (const float*)d_in[4];
    const float* bn1g  = (const float*)d_in[5];
    const float* bn1b  = (const float*)d_in[6];
    const float* W2    = (const float*)d_in[7];
    const float* bn2g  = (const float*)d_in[8];
    const float* bn2b  = (const float*)d_in[9];
    const float* Wlast = (const float*)d_in[10];
    const float* eps   = (const float*)d_in[11];
    float* out = (float*)d_out;

    char* ws = (char*)d_ws;
    size_t off = 0;
    auto alloc = [&](size_t bytes) -> char* {
        char* p = ws + off;
        off += (bytes + 255) & ~(size_t)255;
        return p;
    };
    // -- zeroed region first (one memset) --
    int*   deg      = (int*)alloc((size_t)NN * 4);
    float* statsall = (float*)alloc(16 * 256 * 4);  // slot s: [0..C) sum, [C..2C) sumsq
    float* pool     = (float*)alloc((size_t)GG * 3 * 4);
    size_t zero_len = off;
    // -- rest --
    int*    offs   = (int*)alloc((size_t)(NN + 1) * 4);
    int*    cursor = (int*)alloc((size_t)NN * 4);
    int*    bsum   = (int*)alloc(64 * 4);
    int*    srcs   = (int*)alloc((size_t)EE * 4);
    __half* X16    = (__half*)alloc((size_t)NN * 128 * 2);  // fp16 x_in
    __half* A16    = (__half*)alloc((size_t)NN * 128 * 2);  // fp16 raw y2
    __half* B16    = (__half*)alloc((size_t)NN * 128 * 2);  // fp16 h0
    __half* C16    = (__half*)alloc((size_t)NN * 64 * 2);   // fp16 raw y1
    __half* Wpk1   = (__half*)alloc((size_t)7 * 8192 * 2);  // packed W1 frags
    __half* Wpk2   = (__half*)alloc((size_t)6 * 8192 * 2);  // packed W2 frags
    float*  xlast  = (float*)alloc((size_t)NN * 2 * 4);
    (void)ws_size; (void)n_in; (void)in_sizes; (void)out_size;

    hipMemsetAsync(ws, 0, zero_len, stream);

    // CSR build (by dst)
    hist_kernel<<<(EE + 255) / 256, 256, 0, stream>>>(ei, deg);
    scan1_kernel<<<49, 1024, 0, stream>>>(deg, offs, bsum);
    scan3_kernel<<<49, 1024, 0, stream>>>(offs, cursor, bsum);
    scatter_kernel<<<(EE + 255) / 256, 256, 0, stream>>>(ei, cursor, srcs);
    cvt_kernel<<<(NN * 16 + 255) / 256, 256, 0, stream>>>(x_in, X16);
    packW_kernel<<<(7 * 1024 + 255) / 256, 256, 0, stream>>>(W1, Wpk1, 128, 64, 7);
    packW_kernel<<<(6 * 1024 + 255) / 256, 256, 0, stream>>>(W2, Wpk2, 64, 128, 6);

    const int MB = (NN / 16 + 3) / 4;  // 782 blocks, wave = 16 nodes

    for (int i = 0; i < 7; ++i) {
        int s1 = 2 * i, s2 = 2 * i + 1;
        if (i == 0) {
            agg_kernel<false><<<(NN + 3) / 4, 256, 0, stream>>>(X16, offs, srcs, eps, i,
                                                                nullptr, nullptr, nullptr, B16);
        } else {
            agg_kernel<true><<<(NN + 3) / 4, 256, 0, stream>>>(
                A16, offs, srcs, eps, i, statsall + (2 * i - 1) * 256, bn2g + (i - 1) * 128,
                bn2b + (i - 1) * 128, B16);
        }
        gemm1_kernel<<<MB, 256, 0, stream>>>(B16, Wpk1 + (size_t)i * 8192, C16,
                                             statsall + s1 * 256);
        if (i < 6) {
            gemm2_kernel<<<MB, 256, 0, stream>>>(C16, Wpk2 + (size_t)i * 8192,
                                                 statsall + s1 * 256, bn1g + i * 64,
                                                 bn1b + i * 64, A16, statsall + s2 * 256);
        } else {
            gemm_last_kernel<<<(NN + 255) / 256, 256, 0, stream>>>(
                C16, Wlast, statsall + s1 * 256, bn1g + i * 64, bn1b + i * 64, xlast);
        }
    }

    pool_accum_kernel<<<(NN + 255) / 256, 256, 0, stream>>>(xlast, batch, pool);
    pool_fin_kernel<<<1, 128, 0, stream>>>(pool, out);
}